// Round 21
// baseline (56.893 us; speedup 1.0000x reference)
//
#include <hip/hip_runtime.h>

#define BSZ 32
#define NN 512
#define INF 256
#define NH 4
#define HD 512
#define NEG_SLOPE 0.2f

typedef __attribute__((ext_vector_type(8))) short bf16x8;
typedef __attribute__((ext_vector_type(8))) unsigned short ushort8;
typedef __attribute__((ext_vector_type(4))) float f32x4;

static __device__ __forceinline__ unsigned short f2bf(float f) {
    unsigned u = __builtin_bit_cast(unsigned, f);
    return (unsigned short)((u + 0x7FFFu + ((u >> 16) & 1u)) >> 16);
}

static __device__ __forceinline__ bf16x8 pk8(float4 a, float4 b) {
    unsigned d0, d1, d2, d3;
    asm("v_cvt_pk_bf16_f32 %0, %1, %2" : "=v"(d0) : "v"(a.x), "v"(a.y));
    asm("v_cvt_pk_bf16_f32 %0, %1, %2" : "=v"(d1) : "v"(a.z), "v"(a.w));
    asm("v_cvt_pk_bf16_f32 %0, %1, %2" : "=v"(d2) : "v"(b.x), "v"(b.y));
    asm("v_cvt_pk_bf16_f32 %0, %1, %2" : "=v"(d3) : "v"(b.z), "v"(b.w));
    uint4 u; u.x = d0; u.y = d1; u.z = d2; u.w = d3;
    return __builtin_bit_cast(bf16x8, u);
}

static __device__ __forceinline__ void gl_lds16(const void* g, void* l) {
    __builtin_amdgcn_global_load_lds(
        (const __attribute__((address_space(1))) unsigned int*)g,
        (__attribute__((address_space(3))) unsigned int*)l, 16, 0, 0);
}

// ---- fused prologue (R13-proven): [0,2048) adj->maskbytes; [2048,2560) wpack ----
__global__ __launch_bounds__(256) void k_prep(
    const float* __restrict__ w, unsigned short* __restrict__ wB,
    const float* __restrict__ adj, unsigned char* __restrict__ mbB)
{
    const int bid = blockIdx.x;
    if (bid < 2048) {
        const int lane = threadIdx.x & 63, wave = threadIdx.x >> 6;
        const int row0 = bid * 8 + wave * 2;
        #pragma unroll
        for (int rr = 0; rr < 2; ++rr) {
            const float* ap = adj + (size_t)(row0 + rr) * NN + lane * 8;
            float4 a0 = *(const float4*)ap;
            float4 a1 = *(const float4*)(ap + 4);
            unsigned byte = 0;
            byte |= (a0.x > 0.f) ? 1u : 0u;  byte |= (a0.y > 0.f) ? 2u : 0u;
            byte |= (a0.z > 0.f) ? 4u : 0u;  byte |= (a0.w > 0.f) ? 8u : 0u;
            byte |= (a1.x > 0.f) ? 16u : 0u; byte |= (a1.y > 0.f) ? 32u : 0u;
            byte |= (a1.z > 0.f) ? 64u : 0u; byte |= (a1.w > 0.f) ? 128u : 0u;
            mbB[(size_t)(row0 + rr) * 64 + lane] = (unsigned char)byte;
        }
    } else {
        int gid = (bid - 2048) * 256 + threadIdx.x;
        int c = gid & 511, k = gid >> 9;
        int kb = k >> 5, g = (k >> 3) & 3, e = k & 7;
        wB[(((size_t)(kb * 4 + g) * 512) + c) * 8 + e] = f2bf(w[(size_t)k * 512 + c]);
    }
}

// ---- projection GEMM (R13-proven): 32 rows/block, 512 blocks ----
__global__ __launch_bounds__(256) void k_proj(
    const float* __restrict__ x, const unsigned short* __restrict__ wB,
    const float* __restrict__ ai, const float* __restrict__ aj,
    unsigned short* __restrict__ hB, float* __restrict__ ciT, float* __restrict__ cjT)
{
    __shared__ unsigned short hs[NH * 4096];
    const int tid = threadIdx.x;
    const int lane = tid & 63, head = tid >> 6;
    const int l15 = lane & 15, g = lane >> 4;
    const int row0 = blockIdx.x * 32;

    f32x4 acc[2][8] = {};
    const float* xp0 = x + (size_t)(row0 + l15) * INF + g * 8;
    const float* xp1 = xp0 + 16 * INF;
    const unsigned short* bp = wB + ((size_t)g * 512 + head * 128 + l15) * 8;

    #pragma unroll
    for (int kb = 0; kb < 8; ++kb) {
        float4 f0 = *(const float4*)(xp0 + kb * 32);
        float4 f1 = *(const float4*)(xp0 + kb * 32 + 4);
        float4 f2 = *(const float4*)(xp1 + kb * 32);
        float4 f3 = *(const float4*)(xp1 + kb * 32 + 4);
        bf16x8 a0 = pk8(f0, f1);
        bf16x8 a1 = pk8(f2, f3);
        #pragma unroll
        for (int nf = 0; nf < 8; ++nf) {
            bf16x8 bv = *(const bf16x8*)(bp + (size_t)kb * 16384 + nf * 128);
            acc[0][nf] = __builtin_amdgcn_mfma_f32_16x16x32_bf16(a0, bv, acc[0][nf], 0, 0, 0);
            acc[1][nf] = __builtin_amdgcn_mfma_f32_16x16x32_bf16(a1, bv, acc[1][nf], 0, 0, 0);
        }
    }

    float aiv[8], ajv[8];
    #pragma unroll
    for (int nf = 0; nf < 8; ++nf) {
        aiv[nf] = ai[head * 128 + nf * 16 + l15];
        ajv[nf] = aj[head * 128 + nf * 16 + l15];
    }
    const int b = row0 >> 9;
    const int nloc0 = row0 & 511;
    const int kb2 = nloc0 >> 5;

    #pragma unroll
    for (int m = 0; m < 2; ++m) {
        float pi[4] = {0,0,0,0}, pj[4] = {0,0,0,0};
        #pragma unroll
        for (int nf = 0; nf < 8; ++nf)
            #pragma unroll
            for (int reg = 0; reg < 4; ++reg) {
                pi[reg] = fmaf(acc[m][nf][reg], aiv[nf], pi[reg]);
                pj[reg] = fmaf(acc[m][nf][reg], ajv[nf], pj[reg]);
            }
        #pragma unroll
        for (int reg = 0; reg < 4; ++reg) {
            #pragma unroll
            for (int off = 1; off < 16; off <<= 1) {
                pi[reg] += __shfl_xor(pi[reg], off);
                pj[reg] += __shfl_xor(pj[reg], off);
            }
        }
        if (l15 == 0) {
            #pragma unroll
            for (int reg = 0; reg < 4; ++reg) {
                int n = nloc0 + 16 * m + 4 * g + reg;
                ciT[((size_t)(head * BSZ + b) * NN) + n] = pi[reg];
                cjT[((size_t)(head * BSZ + b) * NN) + n] = pj[reg];
            }
        }
        #pragma unroll
        for (int reg = 0; reg < 4; ++reg) {
            int jloc = 16 * m + 4 * g + reg;
            int g2 = jloc >> 3, e = jloc & 7;
            #pragma unroll
            for (int nf = 0; nf < 8; ++nf)
                hs[head * 4096 + nf * 512 + g2 * 128 + l15 * 8 + e] =
                    f2bf(acc[m][nf][reg]);
        }
    }
    __syncthreads();
    {
        ushort8* dst = (ushort8*)(hB + (((size_t)(b * 4 + head) * 16 + kb2) * 4096));
        const ushort8* src = (const ushort8*)(hs + head * 4096);
        #pragma unroll
        for (int it = 0; it < 8; ++it)
            dst[it * 64 + lane] = src[it * 64 + lane];
    }
}

// ---- fused attention, NF-SPLIT for 2x occupancy: 2048 blocks, each block =
// (b, h, 64 rows, half) computing 4 of 8 nf columns. B-slab 4 KB/kb, LDS
// ~15 KB, acc[4] -> 8 blocks/CU, 8 waves/SIMD (2x all prior variants).
__global__ __launch_bounds__(256, 8) void k_attn(
    const unsigned short* __restrict__ hB, const float* __restrict__ ciT,
    const float* __restrict__ cjT, const unsigned* __restrict__ mb,
    const float* __restrict__ bias, float* __restrict__ out)
{
    __shared__ __align__(16) unsigned short Bst[2][2048];  // 8 KB double buffer
    __shared__ __align__(16) float cjh[NN];                // 2 KB
    __shared__ float cih[64];
    __shared__ unsigned maskS[64][17];                     // 4.25 KB padded
    __shared__ float Mpart[4];

    const int tid = threadIdx.x;
    const int lane = tid & 63, wave = tid >> 6;
    const int l15 = lane & 15, g = lane >> 4;

    const int orig = blockIdx.x;                    // 2048 blocks, 2048%8==0
    const int swz = (orig & 7) * 256 + (orig >> 3); // XCD x -> b in {4x..4x+3}
    const int b    = swz >> 6;
    const int rem  = swz & 63;
    const int h    = rem >> 4;
    const int i0   = ((rem >> 1) & 7) * 64;
    const int half = rem & 1;                       // nf columns [half*4, half*4+4)

    const char* gslab = (const char*)(hB + (size_t)(b * NH + h) * 65536)
                        + half * 4096;              // this block's 4 KB half-slab

    // stage half-slab 0 (one gl_lds16 per thread: 256 x 16 B = 4 KB)
    gl_lds16(gslab + tid * 16, (char*)&Bst[0][0] + wave * 1024);

    {   // cj -> LDS + unmasked max (stabilizer upper bound); ci; masks
        const float* src = cjT + (size_t)(h * BSZ + b) * NN;
        float v0 = src[tid], v1 = src[tid + 256];
        cjh[tid] = v0; cjh[tid + 256] = v1;
        float mv = fmaxf(v0, v1);
        #pragma unroll
        for (int off = 32; off; off >>= 1) mv = fmaxf(mv, __shfl_xor(mv, off));
        if (lane == 0) Mpart[wave] = mv;
        if (tid < 64) cih[tid] = ciT[(size_t)(h * BSZ + b) * NN + i0 + tid];
        uint4 m4 = ((const uint4*)(mb + ((size_t)b * NN + i0) * 16))[tid];
        int base = tid * 4, row = base >> 4, wi = base & 15;
        maskS[row][wi] = m4.x; maskS[row][wi + 1] = m4.y;
        maskS[row][wi + 2] = m4.z; maskS[row][wi + 3] = m4.w;
    }
    __syncthreads();   // drains stage-0 vmcnt too

    const float M = fmaxf(fmaxf(Mpart[0], Mpart[1]), fmaxf(Mpart[2], Mpart[3]));
    const float bc = cih[wave * 16 + l15];
    float smx = bc + M;
    const float mrow = fmaxf(smx, NEG_SLOPE * smx);

    float bvv[4];
    #pragma unroll
    for (int nf = 0; nf < 4; ++nf)
        bvv[nf] = bias[h * 128 + (half * 4 + nf) * 16 + l15];

    bf16x8 ones;
    #pragma unroll
    for (int e = 0; e < 8; ++e) ones[e] = (short)0x3F80;

    f32x4 acc[4] = {};
    f32x4 accs = {};
    int cur = 0;
    const unsigned* mrowp = maskS[wave * 16 + l15];

    for (int kb = 0; kb < 16; ++kb) {
        if (kb < 15) {   // prefetch next half-slab into other buffer
            gl_lds16(gslab + (size_t)(kb + 1) * 8192 + tid * 16,
                     (char*)&Bst[cur ^ 1][0] + wave * 1024);
        }

        // A-frag synthesis
        float4 cva = *(const float4*)&cjh[kb * 32 + g * 8];
        float4 cvb = *(const float4*)&cjh[kb * 32 + g * 8 + 4];
        float cj8[8] = {cva.x, cva.y, cva.z, cva.w, cvb.x, cvb.y, cvb.z, cvb.w};
        unsigned byte = (mrowp[kb] >> (g * 8)) & 0xFFu;
        float p[8];
        #pragma unroll
        for (int e = 0; e < 8; ++e) {
            float s = bc + cj8[e];
            s = fmaxf(s, NEG_SLOPE * s);
            float pe = __expf(s - mrow);
            p[e] = ((byte >> e) & 1u) ? pe : 0.f;
        }
        unsigned d0, d1, d2, d3;
        asm("v_cvt_pk_bf16_f32 %0, %1, %2" : "=v"(d0) : "v"(p[0]), "v"(p[1]));
        asm("v_cvt_pk_bf16_f32 %0, %1, %2" : "=v"(d1) : "v"(p[2]), "v"(p[3]));
        asm("v_cvt_pk_bf16_f32 %0, %1, %2" : "=v"(d2) : "v"(p[4]), "v"(p[5]));
        asm("v_cvt_pk_bf16_f32 %0, %1, %2" : "=v"(d3) : "v"(p[6]), "v"(p[7]));
        uint4 u; u.x = d0; u.y = d1; u.z = d2; u.w = d3;
        bf16x8 av = __builtin_bit_cast(bf16x8, u);

        // B-frags from LDS: 4 nf columns, byte = nf*1024 + lane*16
        const char* bb = (const char*)&Bst[cur][0] + lane * 16;
        #pragma unroll
        for (int nf = 0; nf < 4; ++nf) {
            bf16x8 bv = *(const bf16x8*)(bb + nf * 1024);
            acc[nf] = __builtin_amdgcn_mfma_f32_16x16x32_bf16(av, bv, acc[nf], 0, 0, 0);
        }
        accs = __builtin_amdgcn_mfma_f32_16x16x32_bf16(av, ones, accs, 0, 0, 0);

        if (kb < 15) { __syncthreads(); cur ^= 1; }
    }

    #pragma unroll
    for (int reg = 0; reg < 4; ++reg) {
        float sum = accs[reg];
        float inv = sum > 0.f ? 1.f / sum : 0.f;
        const int i = i0 + wave * 16 + g * 4 + reg;
        #pragma unroll
        for (int nf = 0; nf < 4; ++nf) {
            int colg = h * 128 + (half * 4 + nf) * 16 + l15;
            out[(size_t)(b * NN + i) * HD + colg] = acc[nf][reg] * inv + bvv[nf];
        }
    }
}

extern "C" void kernel_launch(void* const* d_in, const int* in_sizes, int n_in,
                              void* d_out, int out_size, void* d_ws, size_t ws_size,
                              hipStream_t stream)
{
    const float* x    = (const float*)d_in[0];
    const float* adj  = (const float*)d_in[1];
    const float* w    = (const float*)d_in[2];
    const float* ai   = (const float*)d_in[3];
    const float* aj   = (const float*)d_in[4];
    const float* bias = (const float*)d_in[5];
    float* out = (float*)d_out;

    char* ws = (char*)d_ws;
    unsigned short* wB = (unsigned short*)ws;                       //   262,144 B
    unsigned short* hB = (unsigned short*)(ws + 262144);            // 16,777,216 B
    float* ciT         = (float*)(ws + 17039360);                   //   262,144 B
    float* cjT         = (float*)(ws + 17301504);                   //   262,144 B
    unsigned char* mbB = (unsigned char*)(ws + 17563648);           // 1,048,576 B

    k_prep<<<2560, 256, 0, stream>>>(w, wB, adj, mbB);
    k_proj<<<BSZ * NN / 32, 256, 0, stream>>>(x, wB, ai, aj, hB, ciT, cjT);
    k_attn<<<BSZ * NH * (NN / 64) * 2, 256, 0, stream>>>(hB, ciT, cjT,
                                                         (const unsigned*)mbB, bias, out);
}

// Round 22
// 55.805 us; speedup vs baseline: 1.0195x; 1.0195x over previous
//
#include <hip/hip_runtime.h>

#define BSZ 32
#define NN 512
#define INF 256
#define NH 4
#define HD 512
#define NEG_SLOPE 0.2f

typedef __attribute__((ext_vector_type(8))) short bf16x8;
typedef __attribute__((ext_vector_type(8))) unsigned short ushort8;
typedef __attribute__((ext_vector_type(4))) float f32x4;

static __device__ __forceinline__ unsigned short f2bf(float f) {
    unsigned u = __builtin_bit_cast(unsigned, f);
    return (unsigned short)((u + 0x7FFFu + ((u >> 16) & 1u)) >> 16);
}

static __device__ __forceinline__ bf16x8 pk8(float4 a, float4 b) {
    unsigned d0, d1, d2, d3;
    asm("v_cvt_pk_bf16_f32 %0, %1, %2" : "=v"(d0) : "v"(a.x), "v"(a.y));
    asm("v_cvt_pk_bf16_f32 %0, %1, %2" : "=v"(d1) : "v"(a.z), "v"(a.w));
    asm("v_cvt_pk_bf16_f32 %0, %1, %2" : "=v"(d2) : "v"(b.x), "v"(b.y));
    asm("v_cvt_pk_bf16_f32 %0, %1, %2" : "=v"(d3) : "v"(b.z), "v"(b.w));
    uint4 u; u.x = d0; u.y = d1; u.z = d2; u.w = d3;
    return __builtin_bit_cast(bf16x8, u);
}

static __device__ __forceinline__ void gl_lds16(const void* g, void* l) {
    __builtin_amdgcn_global_load_lds(
        (const __attribute__((address_space(1))) unsigned int*)g,
        (__attribute__((address_space(3))) unsigned int*)l, 16, 0, 0);
}

// ---- fused prologue (R13-proven): [0,2048) adj->maskbytes; [2048,2560) wpack ----
__global__ __launch_bounds__(256) void k_prep(
    const float* __restrict__ w, unsigned short* __restrict__ wB,
    const float* __restrict__ adj, unsigned char* __restrict__ mbB)
{
    const int bid = blockIdx.x;
    if (bid < 2048) {
        const int lane = threadIdx.x & 63, wave = threadIdx.x >> 6;
        const int row0 = bid * 8 + wave * 2;
        #pragma unroll
        for (int rr = 0; rr < 2; ++rr) {
            const float* ap = adj + (size_t)(row0 + rr) * NN + lane * 8;
            float4 a0 = *(const float4*)ap;
            float4 a1 = *(const float4*)(ap + 4);
            unsigned byte = 0;
            byte |= (a0.x > 0.f) ? 1u : 0u;  byte |= (a0.y > 0.f) ? 2u : 0u;
            byte |= (a0.z > 0.f) ? 4u : 0u;  byte |= (a0.w > 0.f) ? 8u : 0u;
            byte |= (a1.x > 0.f) ? 16u : 0u; byte |= (a1.y > 0.f) ? 32u : 0u;
            byte |= (a1.z > 0.f) ? 64u : 0u; byte |= (a1.w > 0.f) ? 128u : 0u;
            mbB[(size_t)(row0 + rr) * 64 + lane] = (unsigned char)byte;
        }
    } else {
        int gid = (bid - 2048) * 256 + threadIdx.x;
        int c = gid & 511, k = gid >> 9;
        int kb = k >> 5, g = (k >> 3) & 3, e = k & 7;
        wB[(((size_t)(kb * 4 + g) * 512) + c) * 8 + e] = f2bf(w[(size_t)k * 512 + c]);
    }
}

// ---- projection GEMM (R13-proven): 32 rows/block, 512 blocks ----
__global__ __launch_bounds__(256) void k_proj(
    const float* __restrict__ x, const unsigned short* __restrict__ wB,
    const float* __restrict__ ai, const float* __restrict__ aj,
    unsigned short* __restrict__ hB, float* __restrict__ ciT, float* __restrict__ cjT)
{
    __shared__ unsigned short hs[NH * 4096];
    const int tid = threadIdx.x;
    const int lane = tid & 63, head = tid >> 6;
    const int l15 = lane & 15, g = lane >> 4;
    const int row0 = blockIdx.x * 32;

    f32x4 acc[2][8] = {};
    const float* xp0 = x + (size_t)(row0 + l15) * INF + g * 8;
    const float* xp1 = xp0 + 16 * INF;
    const unsigned short* bp = wB + ((size_t)g * 512 + head * 128 + l15) * 8;

    #pragma unroll
    for (int kb = 0; kb < 8; ++kb) {
        float4 f0 = *(const float4*)(xp0 + kb * 32);
        float4 f1 = *(const float4*)(xp0 + kb * 32 + 4);
        float4 f2 = *(const float4*)(xp1 + kb * 32);
        float4 f3 = *(const float4*)(xp1 + kb * 32 + 4);
        bf16x8 a0 = pk8(f0, f1);
        bf16x8 a1 = pk8(f2, f3);
        #pragma unroll
        for (int nf = 0; nf < 8; ++nf) {
            bf16x8 bv = *(const bf16x8*)(bp + (size_t)kb * 16384 + nf * 128);
            acc[0][nf] = __builtin_amdgcn_mfma_f32_16x16x32_bf16(a0, bv, acc[0][nf], 0, 0, 0);
            acc[1][nf] = __builtin_amdgcn_mfma_f32_16x16x32_bf16(a1, bv, acc[1][nf], 0, 0, 0);
        }
    }

    float aiv[8], ajv[8];
    #pragma unroll
    for (int nf = 0; nf < 8; ++nf) {
        aiv[nf] = ai[head * 128 + nf * 16 + l15];
        ajv[nf] = aj[head * 128 + nf * 16 + l15];
    }
    const int b = row0 >> 9;
    const int nloc0 = row0 & 511;
    const int kb2 = nloc0 >> 5;

    #pragma unroll
    for (int m = 0; m < 2; ++m) {
        float pi[4] = {0,0,0,0}, pj[4] = {0,0,0,0};
        #pragma unroll
        for (int nf = 0; nf < 8; ++nf)
            #pragma unroll
            for (int reg = 0; reg < 4; ++reg) {
                pi[reg] = fmaf(acc[m][nf][reg], aiv[nf], pi[reg]);
                pj[reg] = fmaf(acc[m][nf][reg], ajv[nf], pj[reg]);
            }
        #pragma unroll
        for (int reg = 0; reg < 4; ++reg) {
            #pragma unroll
            for (int off = 1; off < 16; off <<= 1) {
                pi[reg] += __shfl_xor(pi[reg], off);
                pj[reg] += __shfl_xor(pj[reg], off);
            }
        }
        if (l15 == 0) {
            #pragma unroll
            for (int reg = 0; reg < 4; ++reg) {
                int n = nloc0 + 16 * m + 4 * g + reg;
                ciT[((size_t)(head * BSZ + b) * NN) + n] = pi[reg];
                cjT[((size_t)(head * BSZ + b) * NN) + n] = pj[reg];
            }
        }
        #pragma unroll
        for (int reg = 0; reg < 4; ++reg) {
            int jloc = 16 * m + 4 * g + reg;
            int g2 = jloc >> 3, e = jloc & 7;
            #pragma unroll
            for (int nf = 0; nf < 8; ++nf)
                hs[head * 4096 + nf * 512 + g2 * 128 + l15 * 8 + e] =
                    f2bf(acc[m][nf][reg]);
        }
    }
    __syncthreads();
    {
        ushort8* dst = (ushort8*)(hB + (((size_t)(b * 4 + head) * 16 + kb2) * 4096));
        const ushort8* src = (const ushort8*)(hs + head * 4096);
        #pragma unroll
        for (int it = 0; it < 8; ++it)
            dst[it * 64 + lane] = src[it * 64 + lane];
    }
}

// ---- fused attention, COARSE 4-kb PHASES: stage 4 slabs (32 KB) per barrier,
// double-buffered (64 KB LDS). Only 3 in-loop barrier-drains instead of 15,
// each amortized over 4 kb-steps (36 MFMAs). Mask words; ones-MFMA row sums.
__global__ __launch_bounds__(256, 2) void k_attn(
    const unsigned short* __restrict__ hB, const float* __restrict__ ciT,
    const float* __restrict__ cjT, const unsigned* __restrict__ mb,
    const float* __restrict__ bias, float* __restrict__ out)
{
    __shared__ __align__(16) unsigned short Bst[2][16384];  // 2 x 32 KB (4 slabs)
    __shared__ __align__(16) float cjh[NN];                 // 2 KB
    __shared__ float cih[64];
    __shared__ unsigned maskS[64][17];                      // 4.25 KB padded
    __shared__ float Mpart[4];

    const int tid = threadIdx.x;
    const int lane = tid & 63, wave = tid >> 6;
    const int l15 = lane & 15, g = lane >> 4;

    const int orig = blockIdx.x;                    // 1024 blocks, bijective
    const int swz = (orig & 7) * 128 + (orig >> 3); // XCD x -> b in {4x..4x+3}
    const int b  = swz >> 5;
    const int h  = (swz >> 3) & 3;
    const int i0 = (swz & 7) * 64;

    const char* gslab = (const char*)(hB + (size_t)(b * NH + h) * 65536);

    // stage phase 0 (slabs 0..3, 32 KB) into buffer 0
    #pragma unroll
    for (int sl = 0; sl < 4; ++sl) {
        const char* gs = gslab + (size_t)sl * 8192 + wave * 2048 + lane * 16;
        char* ld = (char*)&Bst[0][0] + sl * 8192 + wave * 2048;
        gl_lds16(gs, ld);
        gl_lds16(gs + 1024, ld + 1024);
    }

    {   // cj -> LDS + unmasked max (stabilizer upper bound); ci; masks
        const float* src = cjT + (size_t)(h * BSZ + b) * NN;
        float v0 = src[tid], v1 = src[tid + 256];
        cjh[tid] = v0; cjh[tid + 256] = v1;
        float mv = fmaxf(v0, v1);
        #pragma unroll
        for (int off = 32; off; off >>= 1) mv = fmaxf(mv, __shfl_xor(mv, off));
        if (lane == 0) Mpart[wave] = mv;
        if (tid < 64) cih[tid] = ciT[(size_t)(h * BSZ + b) * NN + i0 + tid];
        uint4 m4 = ((const uint4*)(mb + ((size_t)b * NN + i0) * 16))[tid];
        int base = tid * 4, row = base >> 4, wi = base & 15;
        maskS[row][wi] = m4.x; maskS[row][wi + 1] = m4.y;
        maskS[row][wi + 2] = m4.z; maskS[row][wi + 3] = m4.w;
    }
    __syncthreads();   // drains phase-0 stage + setup

    const float M = fmaxf(fmaxf(Mpart[0], Mpart[1]), fmaxf(Mpart[2], Mpart[3]));
    const float bc = cih[wave * 16 + l15];
    float smx = bc + M;
    const float mrow = fmaxf(smx, NEG_SLOPE * smx);

    float bvv[8];
    #pragma unroll
    for (int nf = 0; nf < 8; ++nf) bvv[nf] = bias[h * 128 + nf * 16 + l15];

    bf16x8 ones;
    #pragma unroll
    for (int e = 0; e < 8; ++e) ones[e] = (short)0x3F80;

    f32x4 acc[8] = {};
    f32x4 accs = {};
    int cur = 0;
    const unsigned* mrowp = maskS[wave * 16 + l15];

    #pragma unroll
    for (int p = 0; p < 4; ++p) {
        if (p < 3) {   // stage next 4 slabs into other buffer (issued early,
                       // drained only at the barrier AFTER this phase's compute)
            #pragma unroll
            for (int sl = 0; sl < 4; ++sl) {
                const char* gs = gslab + (size_t)(p * 4 + 4 + sl) * 8192
                                 + wave * 2048 + lane * 16;
                char* ld = (char*)&Bst[cur ^ 1][0] + sl * 8192 + wave * 2048;
                gl_lds16(gs, ld);
                gl_lds16(gs + 1024, ld + 1024);
            }
        }

        // compute 4 kb-steps from current buffer
        #pragma unroll
        for (int kk = 0; kk < 4; ++kk) {
            const int kb = p * 4 + kk;
            float4 cva = *(const float4*)&cjh[kb * 32 + g * 8];
            float4 cvb = *(const float4*)&cjh[kb * 32 + g * 8 + 4];
            float cj8[8] = {cva.x, cva.y, cva.z, cva.w, cvb.x, cvb.y, cvb.z, cvb.w};
            unsigned byte = (mrowp[kb] >> (g * 8)) & 0xFFu;
            float pr[8];
            #pragma unroll
            for (int e = 0; e < 8; ++e) {
                float s = bc + cj8[e];
                s = fmaxf(s, NEG_SLOPE * s);
                float pe = __expf(s - mrow);
                pr[e] = ((byte >> e) & 1u) ? pe : 0.f;
            }
            unsigned d0, d1, d2, d3;
            asm("v_cvt_pk_bf16_f32 %0, %1, %2" : "=v"(d0) : "v"(pr[0]), "v"(pr[1]));
            asm("v_cvt_pk_bf16_f32 %0, %1, %2" : "=v"(d1) : "v"(pr[2]), "v"(pr[3]));
            asm("v_cvt_pk_bf16_f32 %0, %1, %2" : "=v"(d2) : "v"(pr[4]), "v"(pr[5]));
            asm("v_cvt_pk_bf16_f32 %0, %1, %2" : "=v"(d3) : "v"(pr[6]), "v"(pr[7]));
            uint4 u; u.x = d0; u.y = d1; u.z = d2; u.w = d3;
            bf16x8 av = __builtin_bit_cast(bf16x8, u);

            const char* bb = (const char*)&Bst[cur][0] + kk * 8192 + lane * 16;
            #pragma unroll
            for (int nf = 0; nf < 8; ++nf) {
                bf16x8 bv = *(const bf16x8*)(bb + nf * 1024);
                acc[nf] = __builtin_amdgcn_mfma_f32_16x16x32_bf16(av, bv, acc[nf], 0, 0, 0);
            }
            accs = __builtin_amdgcn_mfma_f32_16x16x32_bf16(av, ones, accs, 0, 0, 0);
        }

        if (p < 3) { __syncthreads(); cur ^= 1; }   // 3 drains total (was 15)
    }

    #pragma unroll
    for (int reg = 0; reg < 4; ++reg) {
        float sum = accs[reg];
        float inv = sum > 0.f ? 1.f / sum : 0.f;
        const int i = i0 + wave * 16 + g * 4 + reg;
        #pragma unroll
        for (int nf = 0; nf < 8; ++nf) {
            int colg = h * 128 + nf * 16 + l15;
            out[(size_t)(b * NN + i) * HD + colg] = acc[nf][reg] * inv + bvv[nf];
        }
    }
}

extern "C" void kernel_launch(void* const* d_in, const int* in_sizes, int n_in,
                              void* d_out, int out_size, void* d_ws, size_t ws_size,
                              hipStream_t stream)
{
    const float* x    = (const float*)d_in[0];
    const float* adj  = (const float*)d_in[1];
    const float* w    = (const float*)d_in[2];
    const float* ai   = (const float*)d_in[3];
    const float* aj   = (const float*)d_in[4];
    const float* bias = (const float*)d_in[5];
    float* out = (float*)d_out;

    char* ws = (char*)d_ws;
    unsigned short* wB = (unsigned short*)ws;                       //   262,144 B
    unsigned short* hB = (unsigned short*)(ws + 262144);            // 16,777,216 B
    float* ciT         = (float*)(ws + 17039360);                   //   262,144 B
    float* cjT         = (float*)(ws + 17301504);                   //   262,144 B
    unsigned char* mbB = (unsigned char*)(ws + 17563648);           // 1,048,576 B

    k_prep<<<2560, 256, 0, stream>>>(w, wB, adj, mbB);
    k_proj<<<BSZ * NN / 32, 256, 0, stream>>>(x, wB, ai, aj, hB, ciT, cjT);
    k_attn<<<BSZ * NH * (NN / 64), 256, 0, stream>>>(hB, ciT, cjT,
                                                     (const unsigned*)mbB, bias, out);
}

// Round 24
// 49.712 us; speedup vs baseline: 1.1445x; 1.1226x over previous
//
#include <hip/hip_runtime.h>

#define BSZ 32
#define NN 512
#define INF 256
#define NH 4
#define HD 512
#define NEG_SLOPE 0.2f

typedef __attribute__((ext_vector_type(8))) short bf16x8;
typedef __attribute__((ext_vector_type(8))) unsigned short ushort8;
typedef __attribute__((ext_vector_type(4))) float f32x4;

static __device__ __forceinline__ unsigned short f2bf(float f) {
    unsigned u = __builtin_bit_cast(unsigned, f);
    return (unsigned short)((u + 0x7FFFu + ((u >> 16) & 1u)) >> 16);
}

static __device__ __forceinline__ bf16x8 pk8(float4 a, float4 b) {
    unsigned d0, d1, d2, d3;
    asm("v_cvt_pk_bf16_f32 %0, %1, %2" : "=v"(d0) : "v"(a.x), "v"(a.y));
    asm("v_cvt_pk_bf16_f32 %0, %1, %2" : "=v"(d1) : "v"(a.z), "v"(a.w));
    asm("v_cvt_pk_bf16_f32 %0, %1, %2" : "=v"(d2) : "v"(b.x), "v"(b.y));
    asm("v_cvt_pk_bf16_f32 %0, %1, %2" : "=v"(d3) : "v"(b.z), "v"(b.w));
    uint4 u; u.x = d0; u.y = d1; u.z = d2; u.w = d3;
    return __builtin_bit_cast(bf16x8, u);
}

static __device__ __forceinline__ void gl_lds16(const void* g, void* l) {
    __builtin_amdgcn_global_load_lds(
        (const __attribute__((address_space(1))) unsigned int*)g,
        (__attribute__((address_space(3))) unsigned int*)l, 16, 0, 0);
}

// ---- fused prologue: blocks [0,2048) adj->maskbytes; [2048,2560) w-pack ----
__global__ __launch_bounds__(256) void k_prep(
    const float* __restrict__ w, unsigned short* __restrict__ wB,
    const float* __restrict__ adj, unsigned char* __restrict__ mbB)
{
    const int bid = blockIdx.x;
    if (bid < 2048) {
        const int lane = threadIdx.x & 63, wave = threadIdx.x >> 6;
        const int row0 = bid * 8 + wave * 2;
        #pragma unroll
        for (int rr = 0; rr < 2; ++rr) {
            const float* ap = adj + (size_t)(row0 + rr) * NN + lane * 8;
            float4 a0 = *(const float4*)ap;
            float4 a1 = *(const float4*)(ap + 4);
            unsigned byte = 0;
            byte |= (a0.x > 0.f) ? 1u : 0u;  byte |= (a0.y > 0.f) ? 2u : 0u;
            byte |= (a0.z > 0.f) ? 4u : 0u;  byte |= (a0.w > 0.f) ? 8u : 0u;
            byte |= (a1.x > 0.f) ? 16u : 0u; byte |= (a1.y > 0.f) ? 32u : 0u;
            byte |= (a1.z > 0.f) ? 64u : 0u; byte |= (a1.w > 0.f) ? 128u : 0u;
            mbB[(size_t)(row0 + rr) * 64 + lane] = (unsigned char)byte;
        }
    } else {
        int gid = (bid - 2048) * 256 + threadIdx.x;
        int c = gid & 511, k = gid >> 9;
        int kb = k >> 5, g = (k >> 3) & 3, e = k & 7;
        wB[(((size_t)(kb * 4 + g) * 512) + c) * 8 + e] = f2bf(w[(size_t)k * 512 + c]);
    }
}

// ---- projection GEMM (proven): 32 rows/block, 512 blocks; LDS-staged hB ----
__global__ __launch_bounds__(256) void k_proj(
    const float* __restrict__ x, const unsigned short* __restrict__ wB,
    const float* __restrict__ ai, const float* __restrict__ aj,
    unsigned short* __restrict__ hB, float* __restrict__ ciT, float* __restrict__ cjT)
{
    __shared__ unsigned short hs[NH * 4096];
    const int tid = threadIdx.x;
    const int lane = tid & 63, head = tid >> 6;
    const int l15 = lane & 15, g = lane >> 4;
    const int row0 = blockIdx.x * 32;

    f32x4 acc[2][8] = {};
    const float* xp0 = x + (size_t)(row0 + l15) * INF + g * 8;
    const float* xp1 = xp0 + 16 * INF;
    const unsigned short* bp = wB + ((size_t)g * 512 + head * 128 + l15) * 8;

    #pragma unroll
    for (int kb = 0; kb < 8; ++kb) {
        float4 f0 = *(const float4*)(xp0 + kb * 32);
        float4 f1 = *(const float4*)(xp0 + kb * 32 + 4);
        float4 f2 = *(const float4*)(xp1 + kb * 32);
        float4 f3 = *(const float4*)(xp1 + kb * 32 + 4);
        bf16x8 a0 = pk8(f0, f1);
        bf16x8 a1 = pk8(f2, f3);
        #pragma unroll
        for (int nf = 0; nf < 8; ++nf) {
            bf16x8 bv = *(const bf16x8*)(bp + (size_t)kb * 16384 + nf * 128);
            acc[0][nf] = __builtin_amdgcn_mfma_f32_16x16x32_bf16(a0, bv, acc[0][nf], 0, 0, 0);
            acc[1][nf] = __builtin_amdgcn_mfma_f32_16x16x32_bf16(a1, bv, acc[1][nf], 0, 0, 0);
        }
    }

    float aiv[8], ajv[8];
    #pragma unroll
    for (int nf = 0; nf < 8; ++nf) {
        aiv[nf] = ai[head * 128 + nf * 16 + l15];
        ajv[nf] = aj[head * 128 + nf * 16 + l15];
    }
    const int b = row0 >> 9;
    const int nloc0 = row0 & 511;
    const int kb2 = nloc0 >> 5;

    #pragma unroll
    for (int m = 0; m < 2; ++m) {
        float pi[4] = {0,0,0,0}, pj[4] = {0,0,0,0};
        #pragma unroll
        for (int nf = 0; nf < 8; ++nf)
            #pragma unroll
            for (int reg = 0; reg < 4; ++reg) {
                pi[reg] = fmaf(acc[m][nf][reg], aiv[nf], pi[reg]);
                pj[reg] = fmaf(acc[m][nf][reg], ajv[nf], pj[reg]);
            }
        #pragma unroll
        for (int reg = 0; reg < 4; ++reg) {
            #pragma unroll
            for (int off = 1; off < 16; off <<= 1) {
                pi[reg] += __shfl_xor(pi[reg], off);
                pj[reg] += __shfl_xor(pj[reg], off);
            }
        }
        if (l15 == 0) {
            #pragma unroll
            for (int reg = 0; reg < 4; ++reg) {
                int n = nloc0 + 16 * m + 4 * g + reg;
                ciT[((size_t)(head * BSZ + b) * NN) + n] = pi[reg];
                cjT[((size_t)(head * BSZ + b) * NN) + n] = pj[reg];
            }
        }
        #pragma unroll
        for (int reg = 0; reg < 4; ++reg) {
            int jloc = 16 * m + 4 * g + reg;
            int g2 = jloc >> 3, e = jloc & 7;
            #pragma unroll
            for (int nf = 0; nf < 8; ++nf)
                hs[head * 4096 + nf * 512 + g2 * 128 + l15 * 8 + e] =
                    f2bf(acc[m][nf][reg]);
        }
    }
    __syncthreads();
    {
        ushort8* dst = (ushort8*)(hB + (((size_t)(b * 4 + head) * 16 + kb2) * 4096));
        const ushort8* src = (const ushort8*)(hs + head * 4096);
        #pragma unroll
        for (int it = 0; it < 8; ++it)
            dst[it * 64 + lane] = src[it * 64 + lane];
    }
}

// ---- fused attention (best-measured R16): 4-slab ring, 3-deep prefetch,
// counted vmcnt (never 0 in steady state), raw barrier + sched fence ----
__global__ __launch_bounds__(256, 4) void k_attn(
    const unsigned short* __restrict__ hB, const float* __restrict__ ciT,
    const float* __restrict__ cjT, const unsigned* __restrict__ mb,
    const float* __restrict__ bias, float* __restrict__ out)
{
    __shared__ __align__(16) unsigned short Bst[4][4096];  // 32 KB, 4-slab ring
    __shared__ __align__(16) float cjh[NN];                // 2 KB
    __shared__ float cih[64];
    __shared__ unsigned maskS[64][17];                     // 4.25 KB, padded
    __shared__ float Mpart[4];

    const int tid = threadIdx.x;
    const int lane = tid & 63, wave = tid >> 6;
    const int l15 = lane & 15, g = lane >> 4;

    const int orig = blockIdx.x;                    // 1024 blocks, bijective
    const int swz = (orig & 7) * 128 + (orig >> 3); // XCD x -> b in {4x..4x+3}
    const int b  = swz >> 5;
    const int h  = (swz >> 3) & 3;
    const int i0 = (swz & 7) * 64;

    const char* gslab = (const char*)(hB + (size_t)(b * NH + h) * 65536);

    #pragma unroll
    for (int s = 0; s < 3; ++s) {
        const char* gs = gslab + (size_t)s * 8192 + wave * 2048 + lane * 16;
        char* ld = (char*)&Bst[s][0] + wave * 2048;
        gl_lds16(gs, ld);
        gl_lds16(gs + 1024, ld + 1024);
    }

    {   // cj -> LDS + unmasked max (stabilizer upper bound); masks; ci
        const float* src = cjT + (size_t)(h * BSZ + b) * NN;
        float v0 = src[tid], v1 = src[tid + 256];
        cjh[tid] = v0; cjh[tid + 256] = v1;
        float mv = fmaxf(v0, v1);
        #pragma unroll
        for (int off = 32; off; off >>= 1) mv = fmaxf(mv, __shfl_xor(mv, off));
        if (lane == 0) Mpart[wave] = mv;
        if (tid < 64) cih[tid] = ciT[(size_t)(h * BSZ + b) * NN + i0 + tid];
        uint4 m4 = ((const uint4*)(mb + ((size_t)b * NN + i0) * 16))[tid];
        int base = tid * 4, row = base >> 4, wi = base & 15;
        maskS[row][wi] = m4.x; maskS[row][wi + 1] = m4.y;
        maskS[row][wi + 2] = m4.z; maskS[row][wi + 3] = m4.w;
    }
    __syncthreads();   // single full drain (setup + slabs 0-2)

    const float M = fmaxf(fmaxf(Mpart[0], Mpart[1]), fmaxf(Mpart[2], Mpart[3]));
    const float bc = cih[wave * 16 + l15];
    float smx = bc + M;
    const float mrow = fmaxf(smx, NEG_SLOPE * smx);

    float bvv[8];
    #pragma unroll
    for (int nf = 0; nf < 8; ++nf) bvv[nf] = bias[h * 128 + nf * 16 + l15];

    bf16x8 ones;
    #pragma unroll
    for (int e = 0; e < 8; ++e) ones[e] = (short)0x3F80;

    f32x4 acc[8] = {};
    f32x4 accs = {};
    const unsigned* mrowp = maskS[wave * 16 + l15];

    #pragma unroll
    for (int kb = 0; kb < 16; ++kb) {
        const int rem = 15 - kb;
        if (rem >= 2)      asm volatile("s_waitcnt vmcnt(4)" ::: "memory");
        else if (rem == 1) asm volatile("s_waitcnt vmcnt(2)" ::: "memory");
        else               asm volatile("s_waitcnt vmcnt(0)" ::: "memory");
        __builtin_amdgcn_s_barrier();          // raw barrier, no drain
        __builtin_amdgcn_sched_barrier(0);     // fence (rule #18)

        if (kb + 3 < 16) {   // stage slab kb+3 into ring slot (kb+3)&3
            const char* gs = gslab + (size_t)(kb + 3) * 8192 + wave * 2048 + lane * 16;
            char* ld = (char*)&Bst[(kb + 3) & 3][0] + wave * 2048;
            gl_lds16(gs, ld);
            gl_lds16(gs + 1024, ld + 1024);
        }

        float4 cva = *(const float4*)&cjh[kb * 32 + g * 8];
        float4 cvb = *(const float4*)&cjh[kb * 32 + g * 8 + 4];
        float cj8[8] = {cva.x, cva.y, cva.z, cva.w, cvb.x, cvb.y, cvb.z, cvb.w};
        unsigned byte = (mrowp[kb] >> (g * 8)) & 0xFFu;
        float p[8];
        #pragma unroll
        for (int e = 0; e < 8; ++e) {
            float s = bc + cj8[e];
            s = fmaxf(s, NEG_SLOPE * s);
            float pe = __expf(s - mrow);
            p[e] = ((byte >> e) & 1u) ? pe : 0.f;
        }
        unsigned d0, d1, d2, d3;
        asm("v_cvt_pk_bf16_f32 %0, %1, %2" : "=v"(d0) : "v"(p[0]), "v"(p[1]));
        asm("v_cvt_pk_bf16_f32 %0, %1, %2" : "=v"(d1) : "v"(p[2]), "v"(p[3]));
        asm("v_cvt_pk_bf16_f32 %0, %1, %2" : "=v"(d2) : "v"(p[4]), "v"(p[5]));
        asm("v_cvt_pk_bf16_f32 %0, %1, %2" : "=v"(d3) : "v"(p[6]), "v"(p[7]));
        uint4 u; u.x = d0; u.y = d1; u.z = d2; u.w = d3;
        bf16x8 av = __builtin_bit_cast(bf16x8, u);

        const char* bb = (const char*)&Bst[kb & 3][0] + lane * 16;
        bf16x8 bfr[8];
        #pragma unroll
        for (int nf = 0; nf < 8; ++nf)
            bfr[nf] = *(const bf16x8*)(bb + nf * 1024);

        #pragma unroll
        for (int nf = 0; nf < 8; ++nf)
            acc[nf] = __builtin_amdgcn_mfma_f32_16x16x32_bf16(av, bfr[nf], acc[nf], 0, 0, 0);
        accs = __builtin_amdgcn_mfma_f32_16x16x32_bf16(av, ones, accs, 0, 0, 0);
    }

    #pragma unroll
    for (int reg = 0; reg < 4; ++reg) {
        float sum = accs[reg];
        float inv = sum > 0.f ? 1.f / sum : 0.f;
        const int i = i0 + wave * 16 + g * 4 + reg;
        #pragma unroll
        for (int nf = 0; nf < 8; ++nf) {
            int colg = h * 128 + nf * 16 + l15;
            out[(size_t)(b * NN + i) * HD + colg] = acc[nf][reg] * inv + bvv[nf];
        }
    }
}

extern "C" void kernel_launch(void* const* d_in, const int* in_sizes, int n_in,
                              void* d_out, int out_size, void* d_ws, size_t ws_size,
                              hipStream_t stream)
{
    const float* x    = (const float*)d_in[0];
    const float* adj  = (const float*)d_in[1];
    const float* w    = (const float*)d_in[2];
    const float* ai   = (const float*)d_in[3];
    const float* aj   = (const float*)d_in[4];
    const float* bias = (const float*)d_in[5];
    float* out = (float*)d_out;

    char* ws = (char*)d_ws;
    unsigned short* wB = (unsigned short*)ws;                       //   262,144 B
    unsigned short* hB = (unsigned short*)(ws + 262144);            // 16,777,216 B
    float* ciT         = (float*)(ws + 17039360);                   //   262,144 B
    float* cjT         = (float*)(ws + 17301504);                   //   262,144 B
    unsigned char* mbB = (unsigned char*)(ws + 17563648);           // 1,048,576 B

    k_prep<<<2560, 256, 0, stream>>>(w, wB, adj, mbB);
    k_proj<<<BSZ * NN / 32, 256, 0, stream>>>(x, wB, ai, aj, hB, ciT, cjT);
    k_attn<<<BSZ * NH * (NN / 64), 256, 0, stream>>>(hB, ciT, cjT,
                                                     (const unsigned*)mbB, bias, out);
}